// Round 1
// baseline (254.426 us; speedup 1.0000x reference)
//
#include <hip/hip_runtime.h>

#define NHEAD 16
#define DHEAD 64
#define SEQ 2048
#define DMODEL 1024
#define BATCH 2
#define SCALE 0.125f

typedef __bf16 bf16x8 __attribute__((ext_vector_type(8)));
typedef float f32x4 __attribute__((ext_vector_type(4)));

__device__ inline unsigned short f2bf(float f) {
  unsigned int u = __builtin_bit_cast(unsigned int, f);
  u = (u + 0x7FFFu + ((u >> 16) & 1u)) >> 16;
  return (unsigned short)u;
}

typedef __attribute__((address_space(1))) unsigned int GU32;
typedef __attribute__((address_space(3))) unsigned int LU32;
__device__ inline void gld_lds16(const void* g, void* l) {
  __builtin_amdgcn_global_load_lds((GU32*)g, (LU32*)l, 16, 0, 0);
}

// ---------------- convert x to bf16 ----------------
__global__ __launch_bounds__(256) void k_conv_x(const float* __restrict__ x,
                                                unsigned short* __restrict__ xb) {
  int i = blockIdx.x * 256 + threadIdx.x;  // covers 4096*1024/4 float4s exactly
  float4 v = ((const float4*)x)[i];
  ushort4 o;
  o.x = f2bf(v.x); o.y = f2bf(v.y); o.z = f2bf(v.z); o.w = f2bf(v.w);
  ((ushort4*)xb)[i] = o;
}

// ---------------- transpose weights to N-major bf16 ----------------
__global__ __launch_bounds__(256) void k_trans_w(const float* __restrict__ Wq, const float* __restrict__ Wk,
                                                 const float* __restrict__ Wv, const float* __restrict__ Wo,
                                                 unsigned short* __restrict__ Wqt, unsigned short* __restrict__ Wkt,
                                                 unsigned short* __restrict__ Wvt, unsigned short* __restrict__ Wot) {
  __shared__ float ts[64][65];
  int z = blockIdx.z;
  const float* src = (z == 0) ? Wq : (z == 1) ? Wk : (z == 2) ? Wv : Wo;
  unsigned short* dst = (z == 0) ? Wqt : (z == 1) ? Wkt : (z == 2) ? Wvt : Wot;
  int r0 = blockIdx.y * 64, c0 = blockIdx.x * 64;
  int t = threadIdx.x;
  int tr = t >> 4, tc = (t & 15) * 4;
#pragma unroll
  for (int i = 0; i < 4; i++) {
    int row = tr + i * 16;
    float4 v = *(const float4*)&src[(size_t)(r0 + row) * DMODEL + c0 + tc];
    ts[row][tc + 0] = v.x; ts[row][tc + 1] = v.y; ts[row][tc + 2] = v.z; ts[row][tc + 3] = v.w;
  }
  __syncthreads();
#pragma unroll
  for (int i = 0; i < 4; i++) {
    int nrow = tr + i * 16;  // output row = original col c0+nrow
    ushort4 o;
    o.x = f2bf(ts[tc + 0][nrow]); o.y = f2bf(ts[tc + 1][nrow]);
    o.z = f2bf(ts[tc + 2][nrow]); o.w = f2bf(ts[tc + 3][nrow]);
    *(ushort4*)&dst[(size_t)(c0 + nrow) * DMODEL + r0 + tc] = o;
  }
}

// ---------------- GEMM core: C(128x128) += A(128xK) * Bt(128xK)^T, K=1024 ----------------
__device__ inline void gemm_core(const unsigned short* __restrict__ A, const unsigned short* __restrict__ Bt,
                                 int brow0, int bcol0, unsigned short* As, unsigned short* Bs,
                                 f32x4 acc[4][4]) {
  int tid = threadIdx.x, lane = tid & 63, wave = tid >> 6;
  int wr = wave >> 1, wc = wave & 1;
  for (int kt = 0; kt < DMODEL / 32; ++kt) {
    int k0 = kt * 32;
    if (kt) __syncthreads();
#pragma unroll
    for (int qi = 0; qi < 2; ++qi) {
      int e0 = (wave * 2 + qi) * 512;
      int e = e0 + lane * 8;
      gld_lds16(&A[(size_t)(brow0 + (e >> 5)) * DMODEL + k0 + (e & 31)], &As[e0]);
      gld_lds16(&Bt[(size_t)(bcol0 + (e >> 5)) * DMODEL + k0 + (e & 31)], &Bs[e0]);
    }
    __syncthreads();
    bf16x8 af[4], bff[4];
#pragma unroll
    for (int i = 0; i < 4; i++)
      af[i] = *(const bf16x8*)&As[(wr * 64 + i * 16 + (lane & 15)) * 32 + (lane >> 4) * 8];
#pragma unroll
    for (int j = 0; j < 4; j++)
      bff[j] = *(const bf16x8*)&Bs[(wc * 64 + j * 16 + (lane & 15)) * 32 + (lane >> 4) * 8];
#pragma unroll
    for (int i = 0; i < 4; i++)
#pragma unroll
      for (int j = 0; j < 4; j++)
        acc[i][j] = __builtin_amdgcn_mfma_f32_16x16x32_bf16(af[i], bff[j], acc[i][j], 0, 0, 0);
  }
}

// ---------------- fused QKV projection ----------------
__global__ __launch_bounds__(256) void k_gemm_qkv(const unsigned short* __restrict__ xb,
                                                  const unsigned short* __restrict__ Wqt,
                                                  const unsigned short* __restrict__ Wkt,
                                                  const unsigned short* __restrict__ Wvt,
                                                  unsigned short* __restrict__ Qb,
                                                  unsigned short* __restrict__ Kb,
                                                  unsigned short* __restrict__ Vtb) {
  __shared__ unsigned short As[128 * 32];
  __shared__ unsigned short Bs[128 * 32];
  int bx = blockIdx.x;               // 0..23
  int wsel = bx >> 3;                // 0=Q 1=K 2=V
  int col0 = (bx & 7) * 128;
  int brow0 = blockIdx.y * 128;
  const unsigned short* Bt = (wsel == 0) ? Wqt : (wsel == 1) ? Wkt : Wvt;
  int lane = threadIdx.x & 63, wave = threadIdx.x >> 6;
  int wr = wave >> 1, wc = wave & 1;
  f32x4 acc[4][4] = {};
  gemm_core(xb, Bt, brow0, col0, As, Bs, acc);
#pragma unroll
  for (int i = 0; i < 4; i++)
#pragma unroll
    for (int j = 0; j < 4; j++) {
      int rowb = brow0 + wr * 64 + i * 16 + ((lane >> 4) << 2);
      int c = col0 + wc * 64 + j * 16 + (lane & 15);
      int b = rowb >> 11, n0 = rowb & 2047;
      int h = c >> 6, d = c & 63;
      if (wsel == 2) {
        ushort4 o;
        o.x = f2bf(acc[i][j][0]); o.y = f2bf(acc[i][j][1]);
        o.z = f2bf(acc[i][j][2]); o.w = f2bf(acc[i][j][3]);
        *(ushort4*)&Vtb[((size_t)(b * NHEAD + h) * DHEAD + d) * SEQ + n0] = o;
      } else {
#pragma unroll
        for (int r = 0; r < 4; r++) {
          size_t idx = ((size_t)(b * NHEAD + h) * SEQ + (n0 + r)) * DHEAD + d;
          if (wsel == 0) Qb[idx] = f2bf(acc[i][j][r] * SCALE);
          else           Kb[idx] = f2bf(acc[i][j][r]);
        }
      }
    }
}

// ---------------- flash attention (causal) ----------------
// Q,K: [bh][n][64] bf16 (Q pre-scaled); V: [bh][64][n] bf16; Ob: [b][n][h*64] bf16
__global__ __launch_bounds__(256) void k_attn(const unsigned short* __restrict__ Qb,
                                              const unsigned short* __restrict__ Kb,
                                              const unsigned short* __restrict__ Vtb,
                                              unsigned short* __restrict__ Ob) {
  __shared__ unsigned short Ks[32 * 72];   // [k 0..31][d 0..63] stride 72
  __shared__ unsigned short Vs[64 * 40];   // [d 0..63][k 0..31] stride 40
  __shared__ unsigned short Ps[4][16 * 40];// per-wave [q 0..15][k 0..31] stride 40
  int qt = blockIdx.x, bh = blockIdx.y;
  int tid = threadIdx.x, lane = tid & 63, wave = tid >> 6;
  int q0 = qt * 64;
  const unsigned short* Qh = Qb + (size_t)bh * SEQ * DHEAD;
  const unsigned short* Kh = Kb + (size_t)bh * SEQ * DHEAD;
  const unsigned short* Vh = Vtb + (size_t)bh * DHEAD * SEQ;

  int qrow = q0 + wave * 16 + (lane & 15);
  bf16x8 qf[2];
  qf[0] = *(const bf16x8*)&Qh[(size_t)qrow * DHEAD + (lane >> 4) * 8];
  qf[1] = *(const bf16x8*)&Qh[(size_t)qrow * DHEAD + 32 + (lane >> 4) * 8];

  f32x4 o_acc[4] = {};
  float m_r[4], l_r[4];
#pragma unroll
  for (int r = 0; r < 4; r++) { m_r[r] = -1e30f; l_r[r] = 0.0f; }

  int colk = lane & 15;
  int rowq0 = q0 + wave * 16 + ((lane >> 4) << 2);
  int nk = (q0 + 64) >> 5;
  for (int kc = 0; kc < nk; ++kc) {
    int k0 = kc * 32;
    // reg-path staging (padded LDS strides -> conflict-free ds_reads)
    int kr = tid >> 3, kd = (tid & 7) * 8;
    bf16x8 kreg = *(const bf16x8*)&Kh[(size_t)(k0 + kr) * DHEAD + kd];
    int vd = tid >> 2, vk = (tid & 3) * 8;
    bf16x8 vreg = *(const bf16x8*)&Vh[(size_t)vd * SEQ + k0 + vk];
    __syncthreads();
    *(bf16x8*)&Ks[kr * 72 + kd] = kreg;
    *(bf16x8*)&Vs[vd * 40 + vk] = vreg;
    __syncthreads();

    // S = Q * K^T  (16x32 per wave, two 16x16 tiles)
    f32x4 s[2] = {};
#pragma unroll
    for (int t = 0; t < 2; t++)
#pragma unroll
      for (int dc = 0; dc < 2; dc++) {
        bf16x8 kf = *(const bf16x8*)&Ks[(t * 16 + colk) * 72 + dc * 32 + (lane >> 4) * 8];
        s[t] = __builtin_amdgcn_mfma_f32_16x16x32_bf16(qf[dc], kf, s[t], 0, 0, 0);
      }

    // causal mask + online softmax
    float pmax[4];
#pragma unroll
    for (int r = 0; r < 4; r++) pmax[r] = -1e30f;
#pragma unroll
    for (int t = 0; t < 2; t++) {
      int kg = k0 + t * 16 + colk;
#pragma unroll
      for (int r = 0; r < 4; r++) {
        float v = s[t][r];
        v = (kg > rowq0 + r) ? -1e30f : v;
        s[t][r] = v;
        pmax[r] = fmaxf(pmax[r], v);
      }
    }
#pragma unroll
    for (int off = 1; off < 16; off <<= 1)
#pragma unroll
      for (int r = 0; r < 4; r++) pmax[r] = fmaxf(pmax[r], __shfl_xor(pmax[r], off));

    float rsum[4];
#pragma unroll
    for (int r = 0; r < 4; r++) {
      float mnew = fmaxf(m_r[r], pmax[r]);
      float sf = __expf(m_r[r] - mnew);
      m_r[r] = mnew;
      float p0 = __expf(s[0][r] - mnew);
      float p1 = __expf(s[1][r] - mnew);
      s[0][r] = p0; s[1][r] = p1;
      rsum[r] = p0 + p1;
      l_r[r] *= sf;
#pragma unroll
      for (int n = 0; n < 4; n++) o_acc[n][r] *= sf;
    }
#pragma unroll
    for (int off = 1; off < 16; off <<= 1)
#pragma unroll
      for (int r = 0; r < 4; r++) rsum[r] += __shfl_xor(rsum[r], off);
#pragma unroll
    for (int r = 0; r < 4; r++) l_r[r] += rsum[r];

    // P -> LDS (transpose to A-fragment layout), then PV
#pragma unroll
    for (int t = 0; t < 2; t++)
#pragma unroll
      for (int r = 0; r < 4; r++)
        Ps[wave][(((lane >> 4) << 2) + r) * 40 + t * 16 + colk] = f2bf(s[t][r]);
    bf16x8 pf = *(const bf16x8*)&Ps[wave][(lane & 15) * 40 + (lane >> 4) * 8];
#pragma unroll
    for (int n = 0; n < 4; n++) {
      bf16x8 vf = *(const bf16x8*)&Vs[(n * 16 + colk) * 40 + (lane >> 4) * 8];
      o_acc[n] = __builtin_amdgcn_mfma_f32_16x16x32_bf16(pf, vf, o_acc[n], 0, 0, 0);
    }
  }

  int b = bh >> 4, h = bh & 15;
#pragma unroll
  for (int n = 0; n < 4; n++)
#pragma unroll
    for (int r = 0; r < 4; r++) {
      int q = q0 + wave * 16 + ((lane >> 4) << 2) + r;
      int d = n * 16 + colk;
      float v = o_acc[n][r] / l_r[r];
      Ob[((size_t)(b * SEQ + q)) * DMODEL + h * DHEAD + d] = f2bf(v);
    }
}

// ---------------- output projection ----------------
__global__ __launch_bounds__(256) void k_gemm_out(const unsigned short* __restrict__ Ob,
                                                  const unsigned short* __restrict__ Wot,
                                                  float* __restrict__ out) {
  __shared__ unsigned short As[128 * 32];
  __shared__ unsigned short Bs[128 * 32];
  int col0 = blockIdx.x * 128;
  int brow0 = blockIdx.y * 128;
  int lane = threadIdx.x & 63, wave = threadIdx.x >> 6;
  int wr = wave >> 1, wc = wave & 1;
  f32x4 acc[4][4] = {};
  gemm_core(Ob, Wot, brow0, col0, As, Bs, acc);
#pragma unroll
  for (int i = 0; i < 4; i++)
#pragma unroll
    for (int j = 0; j < 4; j++)
#pragma unroll
      for (int r = 0; r < 4; r++) {
        int row = brow0 + wr * 64 + i * 16 + ((lane >> 4) << 2) + r;
        int c = col0 + wc * 64 + j * 16 + (lane & 15);
        out[(size_t)row * DMODEL + c] = acc[i][j][r];
      }
}

extern "C" void kernel_launch(void* const* d_in, const int* in_sizes, int n_in,
                              void* d_out, int out_size, void* d_ws, size_t ws_size,
                              hipStream_t stream) {
  const float* x  = (const float*)d_in[0];
  const float* Wq = (const float*)d_in[1];
  const float* Wk = (const float*)d_in[2];
  const float* Wv = (const float*)d_in[3];
  const float* Wo = (const float*)d_in[4];
  float* out = (float*)d_out;
  char* ws = (char*)d_ws;
  unsigned short* xb  = (unsigned short*)(ws);
  unsigned short* Wqt = (unsigned short*)(ws + (8ull << 20));
  unsigned short* Wkt = (unsigned short*)(ws + (10ull << 20));
  unsigned short* Wvt = (unsigned short*)(ws + (12ull << 20));
  unsigned short* Wot = (unsigned short*)(ws + (14ull << 20));
  unsigned short* Qb  = (unsigned short*)(ws + (16ull << 20));
  unsigned short* Kb  = (unsigned short*)(ws + (24ull << 20));
  unsigned short* Vtb = (unsigned short*)(ws + (32ull << 20));
  unsigned short* Ob  = (unsigned short*)(ws + (40ull << 20));

  k_conv_x<<<dim3(4096), dim3(256), 0, stream>>>(x, xb);
  k_trans_w<<<dim3(16, 16, 4), dim3(256), 0, stream>>>(Wq, Wk, Wv, Wo, Wqt, Wkt, Wvt, Wot);
  k_gemm_qkv<<<dim3(24, 32), dim3(256), 0, stream>>>(xb, Wqt, Wkt, Wvt, Qb, Kb, Vtb);
  k_attn<<<dim3(32, 32), dim3(256), 0, stream>>>(Qb, Kb, Vtb, Ob);
  k_gemm_out<<<dim3(8, 32), dim3(256), 0, stream>>>(Ob, Wot, out);
}

// Round 2
// 145.141 us; speedup vs baseline: 1.7530x; 1.7530x over previous
//
#include <hip/hip_runtime.h>

#define NHEAD 16
#define DHEAD 64
#define SEQ 2048
#define DMODEL 1024
#define BATCH 2
#define SCALE 0.125f

typedef __bf16 bf16x8 __attribute__((ext_vector_type(8)));
typedef float f32x4 __attribute__((ext_vector_type(4)));
typedef float f32x16 __attribute__((ext_vector_type(16)));

__device__ inline unsigned short f2bf(float f) {
  unsigned int u = __builtin_bit_cast(unsigned int, f);
  u = (u + 0x7FFFu + ((u >> 16) & 1u)) >> 16;
  return (unsigned short)u;
}

__device__ inline unsigned int cvtpk_bf16(float lo, float hi) {
  unsigned int r;
  asm("v_cvt_pk_bf16_f32 %0, %1, %2" : "=v"(r) : "v"(lo), "v"(hi));
  return r;
}

__device__ inline void pl32swap(unsigned int& a, unsigned int& b) {
  asm volatile("v_permlane32_swap_b32 %0, %1" : "+v"(a), "+v"(b));
}

typedef __attribute__((address_space(1))) unsigned int GU32;
typedef __attribute__((address_space(3))) unsigned int LU32;
__device__ inline void gld_lds16(const void* g, void* l) {
  __builtin_amdgcn_global_load_lds((GU32*)g, (LU32*)l, 16, 0, 0);
}

// ---------------- convert x to bf16 ----------------
__global__ __launch_bounds__(256) void k_conv_x(const float* __restrict__ x,
                                                unsigned short* __restrict__ xb) {
  int i = blockIdx.x * 256 + threadIdx.x;
  float4 v = ((const float4*)x)[i];
  ushort4 o;
  o.x = f2bf(v.x); o.y = f2bf(v.y); o.z = f2bf(v.z); o.w = f2bf(v.w);
  ((ushort4*)xb)[i] = o;
}

// ---------------- transpose weights to N-major bf16 ----------------
__global__ __launch_bounds__(256) void k_trans_w(const float* __restrict__ Wq, const float* __restrict__ Wk,
                                                 const float* __restrict__ Wv, const float* __restrict__ Wo,
                                                 unsigned short* __restrict__ Wqt, unsigned short* __restrict__ Wkt,
                                                 unsigned short* __restrict__ Wvt, unsigned short* __restrict__ Wot) {
  __shared__ float ts[64][65];
  int z = blockIdx.z;
  const float* src = (z == 0) ? Wq : (z == 1) ? Wk : (z == 2) ? Wv : Wo;
  unsigned short* dst = (z == 0) ? Wqt : (z == 1) ? Wkt : (z == 2) ? Wvt : Wot;
  int r0 = blockIdx.y * 64, c0 = blockIdx.x * 64;
  int t = threadIdx.x;
  int tr = t >> 4, tc = (t & 15) * 4;
#pragma unroll
  for (int i = 0; i < 4; i++) {
    int row = tr + i * 16;
    float4 v = *(const float4*)&src[(size_t)(r0 + row) * DMODEL + c0 + tc];
    ts[row][tc + 0] = v.x; ts[row][tc + 1] = v.y; ts[row][tc + 2] = v.z; ts[row][tc + 3] = v.w;
  }
  __syncthreads();
#pragma unroll
  for (int i = 0; i < 4; i++) {
    int nrow = tr + i * 16;
    ushort4 o;
    o.x = f2bf(ts[tc + 0][nrow]); o.y = f2bf(ts[tc + 1][nrow]);
    o.z = f2bf(ts[tc + 2][nrow]); o.w = f2bf(ts[tc + 3][nrow]);
    *(ushort4*)&dst[(size_t)(c0 + nrow) * DMODEL + r0 + tc] = o;
  }
}

// ---------------- GEMM core (unchanged m97-style) ----------------
__device__ inline void gemm_core(const unsigned short* __restrict__ A, const unsigned short* __restrict__ Bt,
                                 int brow0, int bcol0, unsigned short* As, unsigned short* Bs,
                                 f32x4 acc[4][4]) {
  int tid = threadIdx.x, lane = tid & 63, wave = tid >> 6;
  int wr = wave >> 1, wc = wave & 1;
  for (int kt = 0; kt < DMODEL / 32; ++kt) {
    int k0 = kt * 32;
    if (kt) __syncthreads();
#pragma unroll
    for (int qi = 0; qi < 2; ++qi) {
      int e0 = (wave * 2 + qi) * 512;
      int e = e0 + lane * 8;
      gld_lds16(&A[(size_t)(brow0 + (e >> 5)) * DMODEL + k0 + (e & 31)], &As[e0]);
      gld_lds16(&Bt[(size_t)(bcol0 + (e >> 5)) * DMODEL + k0 + (e & 31)], &Bs[e0]);
    }
    __syncthreads();
    bf16x8 af[4], bff[4];
#pragma unroll
    for (int i = 0; i < 4; i++)
      af[i] = *(const bf16x8*)&As[(wr * 64 + i * 16 + (lane & 15)) * 32 + (lane >> 4) * 8];
#pragma unroll
    for (int j = 0; j < 4; j++)
      bff[j] = *(const bf16x8*)&Bs[(wc * 64 + j * 16 + (lane & 15)) * 32 + (lane >> 4) * 8];
#pragma unroll
    for (int i = 0; i < 4; i++)
#pragma unroll
      for (int j = 0; j < 4; j++)
        acc[i][j] = __builtin_amdgcn_mfma_f32_16x16x32_bf16(af[i], bff[j], acc[i][j], 0, 0, 0);
  }
}

// ---------------- fused QKV projection ----------------
__global__ __launch_bounds__(256) void k_gemm_qkv(const unsigned short* __restrict__ xb,
                                                  const unsigned short* __restrict__ Wqt,
                                                  const unsigned short* __restrict__ Wkt,
                                                  const unsigned short* __restrict__ Wvt,
                                                  unsigned short* __restrict__ Qb,
                                                  unsigned short* __restrict__ Kb,
                                                  unsigned short* __restrict__ Vtb) {
  __shared__ unsigned short As[128 * 32];
  __shared__ unsigned short Bs[128 * 32];
  int bx = blockIdx.x;
  int wsel = bx >> 3;
  int col0 = (bx & 7) * 128;
  int brow0 = blockIdx.y * 128;
  const unsigned short* Bt = (wsel == 0) ? Wqt : (wsel == 1) ? Wkt : Wvt;
  int lane = threadIdx.x & 63, wave = threadIdx.x >> 6;
  int wr = wave >> 1, wc = wave & 1;
  f32x4 acc[4][4] = {};
  gemm_core(xb, Bt, brow0, col0, As, Bs, acc);
#pragma unroll
  for (int i = 0; i < 4; i++)
#pragma unroll
    for (int j = 0; j < 4; j++) {
      int rowb = brow0 + wr * 64 + i * 16 + ((lane >> 4) << 2);
      int c = col0 + wc * 64 + j * 16 + (lane & 15);
      int b = rowb >> 11, n0 = rowb & 2047;
      int h = c >> 6, d = c & 63;
      if (wsel == 2) {
        ushort4 o;
        o.x = f2bf(acc[i][j][0]); o.y = f2bf(acc[i][j][1]);
        o.z = f2bf(acc[i][j][2]); o.w = f2bf(acc[i][j][3]);
        *(ushort4*)&Vtb[((size_t)(b * NHEAD + h) * DHEAD + d) * SEQ + n0] = o;
      } else {
#pragma unroll
        for (int r = 0; r < 4; r++) {
          size_t idx = ((size_t)(b * NHEAD + h) * SEQ + (n0 + r)) * DHEAD + d;
          if (wsel == 0) Qb[idx] = f2bf(acc[i][j][r] * SCALE);
          else           Kb[idx] = f2bf(acc[i][j][r]);
        }
      }
    }
}

// ---------------- flash attention (causal), swapped-operand 32x32 ----------------
// Q,K: [bh][n][64] bf16 (Q pre-scaled); V: [bh][64][n] bf16; Ob: [b][n][h*64] bf16
#define KPAD 68
__global__ __launch_bounds__(256) void k_attn(const unsigned short* __restrict__ Qb,
                                              const unsigned short* __restrict__ Kb,
                                              const unsigned short* __restrict__ Vtb,
                                              unsigned short* __restrict__ Ob) {
  __shared__ unsigned short Ks[64 * KPAD];  // [k][d]
  __shared__ unsigned short Vs[64 * KPAD];  // [d][k]
  int id = blockIdx.x;
  int qt, bh;
  if (id < 256) { qt = id & 15; bh = id >> 4; }
  else { int j = id - 256; qt = 15 - (j & 15); bh = 16 + (j >> 4); }
  int qblk0 = qt * 128;
  int tid = threadIdx.x, lane = tid & 63, wave = tid >> 6;
  int h = lane >> 5, ql = lane & 31;
  int qw0 = qblk0 + wave * 32;
  int q = qw0 + ql;

  const unsigned short* Qh = Qb + (size_t)bh * SEQ * DHEAD;
  const unsigned short* Kh = Kb + (size_t)bh * SEQ * DHEAD;
  const unsigned short* Vh = Vtb + (size_t)bh * DHEAD * SEQ;

  // Q row in registers: qf[ds] = Q[q][ds*16 + 8h .. +7]
  bf16x8 qf[4];
#pragma unroll
  for (int ds = 0; ds < 4; ds++)
    qf[ds] = *(const bf16x8*)&Qh[(size_t)q * DHEAD + ds * 16 + 8 * h];

  f32x16 o0 = {}, o1 = {};
  float m_r = -1e30f, l_r = 0.0f;

  int nk = 2 * qt + 2;  // number of 64-k chunks
  int rr = tid >> 3, cc = (tid & 7) * 8;

  // stage chunk 0
  bf16x8 kreg0, kreg1, vreg0, vreg1;
  kreg0 = *(const bf16x8*)&Kh[(size_t)(rr) * DHEAD + cc];
  kreg1 = *(const bf16x8*)&Kh[(size_t)(32 + rr) * DHEAD + cc];
  vreg0 = *(const bf16x8*)&Vh[(size_t)rr * SEQ + cc];
  vreg1 = *(const bf16x8*)&Vh[(size_t)(32 + rr) * SEQ + cc];
  *(bf16x8*)&Ks[rr * KPAD + cc] = kreg0;
  *(bf16x8*)&Ks[(32 + rr) * KPAD + cc] = kreg1;
  *(bf16x8*)&Vs[rr * KPAD + cc] = vreg0;
  *(bf16x8*)&Vs[(32 + rr) * KPAD + cc] = vreg1;
  __syncthreads();

  for (int kc = 0; kc < nk; ++kc) {
    int k0 = kc * 64;
    // prefetch next chunk's global data (latency hides under compute)
    if (kc + 1 < nk) {
      int kn = k0 + 64;
      kreg0 = *(const bf16x8*)&Kh[(size_t)(kn + rr) * DHEAD + cc];
      kreg1 = *(const bf16x8*)&Kh[(size_t)(kn + 32 + rr) * DHEAD + cc];
      vreg0 = *(const bf16x8*)&Vh[(size_t)rr * SEQ + kn + cc];
      vreg1 = *(const bf16x8*)&Vh[(size_t)(32 + rr) * SEQ + kn + cc];
    }

    if (k0 <= qw0 + 31) {  // wave has live keys in this chunk
      // ---- S^T = K * Q^T : two 32x32 tiles (k halves) ----
      f32x16 s0 = {}, s1 = {};
#pragma unroll
      for (int ds = 0; ds < 4; ds++) {
        bf16x8 kf0 = *(const bf16x8*)&Ks[(ql) * KPAD + ds * 16 + 8 * h];
        bf16x8 kf1 = *(const bf16x8*)&Ks[(32 + ql) * KPAD + ds * 16 + 8 * h];
        s0 = __builtin_amdgcn_mfma_f32_32x32x16_bf16(kf0, qf[ds], s0, 0, 0, 0);
        s1 = __builtin_amdgcn_mfma_f32_32x32x16_bf16(kf1, qf[ds], s1, 0, 0, 0);
      }
      // ---- causal mask (diagonal chunks only) ----
      if (k0 + 63 > qw0) {
#pragma unroll
        for (int r = 0; r < 16; r++) {
          int kloc = (r & 3) + 8 * (r >> 2) + 4 * h;
          if (k0 + kloc > q) s0[r] = -1e30f;
          if (k0 + 32 + kloc > q) s1[r] = -1e30f;
        }
      }
      // ---- online softmax (per-lane scalar state) ----
      float pmax = s0[0];
#pragma unroll
      for (int r = 1; r < 16; r++) pmax = fmaxf(pmax, s0[r]);
#pragma unroll
      for (int r = 0; r < 16; r++) pmax = fmaxf(pmax, s1[r]);
      pmax = fmaxf(pmax, __shfl_xor(pmax, 32));
      float mnew = fmaxf(m_r, pmax);
      float sf = __expf(m_r - mnew);
      m_r = mnew;
      float rsum = 0.0f;
#pragma unroll
      for (int r = 0; r < 16; r++) { s0[r] = __expf(s0[r] - mnew); rsum += s0[r]; }
#pragma unroll
      for (int r = 0; r < 16; r++) { s1[r] = __expf(s1[r] - mnew); rsum += s1[r]; }
      rsum += __shfl_xor(rsum, 32);
      l_r = l_r * sf + rsum;
#pragma unroll
      for (int r = 0; r < 16; r++) { o0[r] *= sf; o1[r] *= sf; }

      // ---- build P^T B-fragments in-register (cvt_pk + permlane32_swap) ----
      unsigned int pa0 = cvtpk_bf16(s0[0], s0[1]),   pa1 = cvtpk_bf16(s0[2], s0[3]);
      unsigned int pb0 = cvtpk_bf16(s0[4], s0[5]),   pb1 = cvtpk_bf16(s0[6], s0[7]);
      unsigned int pc0 = cvtpk_bf16(s0[8], s0[9]),   pc1 = cvtpk_bf16(s0[10], s0[11]);
      unsigned int pd0 = cvtpk_bf16(s0[12], s0[13]), pd1 = cvtpk_bf16(s0[14], s0[15]);
      unsigned int pe0 = cvtpk_bf16(s1[0], s1[1]),   pe1 = cvtpk_bf16(s1[2], s1[3]);
      unsigned int pf0 = cvtpk_bf16(s1[4], s1[5]),   pf1 = cvtpk_bf16(s1[6], s1[7]);
      unsigned int pg0 = cvtpk_bf16(s1[8], s1[9]),   pg1 = cvtpk_bf16(s1[10], s1[11]);
      unsigned int ph0 = cvtpk_bf16(s1[12], s1[13]), ph1 = cvtpk_bf16(s1[14], s1[15]);
      pl32swap(pa0, pb0); pl32swap(pa1, pb1);
      pl32swap(pc0, pd0); pl32swap(pc1, pd1);
      pl32swap(pe0, pf0); pl32swap(pe1, pf1);
      pl32swap(pg0, ph0); pl32swap(pg1, ph1);
      unsigned int fw[4][4] = {{pa0, pa1, pb0, pb1},
                               {pc0, pc1, pd0, pd1},
                               {pe0, pe1, pf0, pf1},
                               {pg0, pg1, ph0, ph1}};
      // ---- O^T += V^T * P^T ----
#pragma unroll
      for (int ks = 0; ks < 4; ks++) {
        bf16x8 pfrag = __builtin_bit_cast(bf16x8, *(uint4*)fw[ks]);
        bf16x8 vf0 = *(const bf16x8*)&Vs[(ql) * KPAD + ks * 16 + 8 * h];
        bf16x8 vf1 = *(const bf16x8*)&Vs[(32 + ql) * KPAD + ks * 16 + 8 * h];
        o0 = __builtin_amdgcn_mfma_f32_32x32x16_bf16(vf0, pfrag, o0, 0, 0, 0);
        o1 = __builtin_amdgcn_mfma_f32_32x32x16_bf16(vf1, pfrag, o1, 0, 0, 0);
      }
    }

    __syncthreads();
    if (kc + 1 < nk) {
      *(bf16x8*)&Ks[rr * KPAD + cc] = kreg0;
      *(bf16x8*)&Ks[(32 + rr) * KPAD + cc] = kreg1;
      *(bf16x8*)&Vs[rr * KPAD + cc] = vreg0;
      *(bf16x8*)&Vs[(32 + rr) * KPAD + cc] = vreg1;
    }
    __syncthreads();
  }

  // ---- epilogue: O = O^T / l, packed 8B stores ----
  int b = bh >> 4, hh = bh & 15;
  float rl = 1.0f / l_r;
  size_t obase = ((size_t)(b * SEQ + q)) * DMODEL + hh * DHEAD;
#pragma unroll
  for (int rg = 0; rg < 4; rg++) {
    uint2 w0, w1;
    w0.x = cvtpk_bf16(o0[4 * rg] * rl, o0[4 * rg + 1] * rl);
    w0.y = cvtpk_bf16(o0[4 * rg + 2] * rl, o0[4 * rg + 3] * rl);
    w1.x = cvtpk_bf16(o1[4 * rg] * rl, o1[4 * rg + 1] * rl);
    w1.y = cvtpk_bf16(o1[4 * rg + 2] * rl, o1[4 * rg + 3] * rl);
    *(uint2*)&Ob[obase + 8 * rg + 4 * h] = w0;
    *(uint2*)&Ob[obase + 32 + 8 * rg + 4 * h] = w1;
  }
}

// ---------------- output projection ----------------
__global__ __launch_bounds__(256) void k_gemm_out(const unsigned short* __restrict__ Ob,
                                                  const unsigned short* __restrict__ Wot,
                                                  float* __restrict__ out) {
  __shared__ unsigned short As[128 * 32];
  __shared__ unsigned short Bs[128 * 32];
  int col0 = blockIdx.x * 128;
  int brow0 = blockIdx.y * 128;
  int lane = threadIdx.x & 63, wave = threadIdx.x >> 6;
  int wr = wave >> 1, wc = wave & 1;
  f32x4 acc[4][4] = {};
  gemm_core(Ob, Wot, brow0, col0, As, Bs, acc);
#pragma unroll
  for (int i = 0; i < 4; i++)
#pragma unroll
    for (int j = 0; j < 4; j++)
#pragma unroll
      for (int r = 0; r < 4; r++) {
        int row = brow0 + wr * 64 + i * 16 + ((lane >> 4) << 2) + r;
        int c = col0 + wc * 64 + j * 16 + (lane & 15);
        out[(size_t)row * DMODEL + c] = acc[i][j][r];
      }
}

extern "C" void kernel_launch(void* const* d_in, const int* in_sizes, int n_in,
                              void* d_out, int out_size, void* d_ws, size_t ws_size,
                              hipStream_t stream) {
  const float* x  = (const float*)d_in[0];
  const float* Wq = (const float*)d_in[1];
  const float* Wk = (const float*)d_in[2];
  const float* Wv = (const float*)d_in[3];
  const float* Wo = (const float*)d_in[4];
  float* out = (float*)d_out;
  char* ws = (char*)d_ws;
  unsigned short* xb  = (unsigned short*)(ws);
  unsigned short* Wqt = (unsigned short*)(ws + (8ull << 20));
  unsigned short* Wkt = (unsigned short*)(ws + (10ull << 20));
  unsigned short* Wvt = (unsigned short*)(ws + (12ull << 20));
  unsigned short* Wot = (unsigned short*)(ws + (14ull << 20));
  unsigned short* Qb  = (unsigned short*)(ws + (16ull << 20));
  unsigned short* Kb  = (unsigned short*)(ws + (24ull << 20));
  unsigned short* Vtb = (unsigned short*)(ws + (32ull << 20));
  unsigned short* Ob  = (unsigned short*)(ws + (40ull << 20));

  k_conv_x<<<dim3(4096), dim3(256), 0, stream>>>(x, xb);
  k_trans_w<<<dim3(16, 16, 4), dim3(256), 0, stream>>>(Wq, Wk, Wv, Wo, Wqt, Wkt, Wvt, Wot);
  k_gemm_qkv<<<dim3(24, 32), dim3(256), 0, stream>>>(xb, Wqt, Wkt, Wvt, Qb, Kb, Vtb);
  k_attn<<<dim3(512), dim3(256), 0, stream>>>(Qb, Kb, Vtb, Ob);
  k_gemm_out<<<dim3(8, 32), dim3(256), 0, stream>>>(Ob, Wot, out);
}